// Round 3
// baseline (4113.535 us; speedup 1.0000x reference)
//
#include <hip/hip_runtime.h>

// SentenceEncodingRNN2: 2-layer BiLSTM (T=256,B=128,D=300,H=256) + attention pooling.
// Round 12: amortize ring latency. R11 post-mortem: per-step wall 3.0us, compute
//   only ~0.5us (MfmaUtil 10.5/VALU 13) -> ~2.4us/step is ring store->L2->spin
//   round trip, invariant across R9-R11. Fix: (a) 16 VALID batches per MFMA m-tile
//   (R11 wasted 8/16 rows on zero pad); (b) 2 supergroups (32 batches) per block,
//   64 blocks -- 4x batches per block-step against the same per-step latency.
//   blk = s*8 + d*4 + p keeps all 8 exchange partners (same d,p) on one XCD.
//   Weights unchanged: 128 VGPR resident hi/lo bf16 fragments, wave==gate.
//   proj_gemm2 / attn_gemm / attn_final unchanged.

#define T_ 256
#define B_ 128
#define D_ 300
#define H_ 256
#define G4H 1024   // 4*H
#define H2 512     // 2*H
#define TC 64      // time-chunk length
#define LDK 40     // proj/attn LDS k-stride in bf16 (80 B rows)
#define LDA 264    // lstm A-tile LDS k-stride in bf16 (256+8)

typedef __attribute__((ext_vector_type(8))) short bf16x8;
typedef __attribute__((ext_vector_type(4))) short short4v;
typedef __attribute__((ext_vector_type(4))) float f32x4;

#define MFMA16(a, b, c) __builtin_amdgcn_mfma_f32_16x16x32_bf16(a, b, c, 0, 0, 0)

// ---------------- helpers ----------------
__device__ __forceinline__ float sigf(float x) { return 1.f / (1.f + __expf(-x)); }
__device__ __forceinline__ float tanhfast(float x) { return 2.f / (1.f + __expf(-2.f * x)) - 1.f; }

__device__ __forceinline__ short hi_bf16(float x) {
  return (short)(__float_as_uint(x) >> 16);
}
__device__ __forceinline__ short lo_bf16(float x) {
  float lo = x - __uint_as_float(__float_as_uint(x) & 0xFFFF0000u);
  return (short)(__float_as_uint(lo) >> 16);
}

__device__ __forceinline__ void split_f4(const float4 v, short* hp, short* lp) {
  short4v h, l;
  h.x = hi_bf16(v.x); l.x = lo_bf16(v.x);
  h.y = hi_bf16(v.y); l.y = lo_bf16(v.y);
  h.z = hi_bf16(v.z); l.z = lo_bf16(v.z);
  h.w = hi_bf16(v.w); l.w = lo_bf16(v.w);
  *(short4v*)hp = h;
  *(short4v*)lp = l;
}

__device__ __forceinline__ void split8(const float4 v0, const float4 v1,
                                       bf16x8* hp, bf16x8* lp) {
  bf16x8 h, l;
  h[0] = hi_bf16(v0.x); l[0] = lo_bf16(v0.x);
  h[1] = hi_bf16(v0.y); l[1] = lo_bf16(v0.y);
  h[2] = hi_bf16(v0.z); l[2] = lo_bf16(v0.z);
  h[3] = hi_bf16(v0.w); l[3] = lo_bf16(v0.w);
  h[4] = hi_bf16(v1.x); l[4] = lo_bf16(v1.x);
  h[5] = hi_bf16(v1.y); l[5] = lo_bf16(v1.y);
  h[6] = hi_bf16(v1.z); l[6] = lo_bf16(v1.z);
  h[7] = hi_bf16(v1.w); l[7] = lo_bf16(v1.w);
  *hp = h; *lp = l;
}

// ---------------- dual-direction projection GEMM, split-bf16 MFMA ----------------
__global__ __launch_bounds__(256, 2) void proj_gemm2(
    const float* __restrict__ X,
    const float* __restrict__ W0, const float* __restrict__ W1,
    const float* __restrict__ b1f, const float* __restrict__ b2f,
    const float* __restrict__ b1r, const float* __restrict__ b2r,
    float* __restrict__ C0, float* __restrict__ C1,
    int N, int K, const int* __restrict__ lengths, int t0)
{
  __shared__ short Xh[128 * LDK], Xl[128 * LDK];
  __shared__ short Wh[128 * LDK], Wl[128 * LDK];
  const int rev = blockIdx.z;
  const float* __restrict__ W = rev ? W1 : W0;
  const float* __restrict__ bias1 = rev ? b1r : b1f;
  const float* __restrict__ bias2 = rev ? b2r : b2f;
  float* __restrict__ C = rev ? C1 : C0;

  const int tid = threadIdx.x;
  const int m0 = blockIdx.y * 128, n0 = blockIdx.x * 128;
  const int s_step = t0 + blockIdx.y;

  const int sr = tid >> 3;
  const int sc = (tid & 7) * 4;
  const float* px[4];
  const float* pw[4];
#pragma unroll
  for (int p = 0; p < 4; p++) {
    const int r = sr + p * 32;          // r == batch index within tile
    int ss = s_step;
    if (rev) {
      int lb = lengths[r]; if (lb < 1) lb = 1;
      ss = (s_step < lb) ? (lb - 1 - s_step) : s_step;
    }
    px[p] = X + (size_t)(ss * 128 + r) * K;
    pw[p] = W + (size_t)(n0 + r) * K;
  }

  const int lane = tid & 63, w = tid >> 6;
  const int mb = (w & 1) * 64, nb = (w >> 1) * 64;
  const int r16 = lane & 15, quad = lane >> 4;

  f32x4 acc[4][4];
#pragma unroll
  for (int i = 0; i < 4; i++)
#pragma unroll
    for (int j = 0; j < 4; j++) acc[i][j] = (f32x4){0.f, 0.f, 0.f, 0.f};

  for (int k0 = 0; k0 < K; k0 += 32) {
    const int gk = k0 + sc;
    const bool kin = (gk < K);          // K % 4 == 0 -> whole float4 in/out
#pragma unroll
    for (int p = 0; p < 4; p++) {
      float4 xv = {0.f, 0.f, 0.f, 0.f}, wv = {0.f, 0.f, 0.f, 0.f};
      if (kin) { xv = *(const float4*)(px[p] + gk); wv = *(const float4*)(pw[p] + gk); }
      const int ro = (sr + p * 32) * LDK + sc;
      split_f4(xv, &Xh[ro], &Xl[ro]);
      split_f4(wv, &Wh[ro], &Wl[ro]);
    }
    __syncthreads();

    bf16x8 ah[4], al[4], bh[4], bl[4];
#pragma unroll
    for (int mt = 0; mt < 4; mt++) {
      const int ro = (mb + mt * 16 + r16) * LDK + quad * 8;
      ah[mt] = *(const bf16x8*)&Xh[ro];
      al[mt] = *(const bf16x8*)&Xl[ro];
    }
#pragma unroll
    for (int nt = 0; nt < 4; nt++) {
      const int ro = (nb + nt * 16 + r16) * LDK + quad * 8;
      bh[nt] = *(const bf16x8*)&Wh[ro];
      bl[nt] = *(const bf16x8*)&Wl[ro];
    }
#pragma unroll
    for (int mt = 0; mt < 4; mt++)
#pragma unroll
      for (int nt = 0; nt < 4; nt++) {
        acc[mt][nt] = __builtin_amdgcn_mfma_f32_16x16x32_bf16(ah[mt], bh[nt], acc[mt][nt], 0, 0, 0);
        acc[mt][nt] = __builtin_amdgcn_mfma_f32_16x16x32_bf16(ah[mt], bl[nt], acc[mt][nt], 0, 0, 0);
        acc[mt][nt] = __builtin_amdgcn_mfma_f32_16x16x32_bf16(al[mt], bh[nt], acc[mt][nt], 0, 0, 0);
      }
    __syncthreads();
  }

  float bsum[4];
#pragma unroll
  for (int nt = 0; nt < 4; nt++) {
    const int col = n0 + nb + nt * 16 + r16;
    bsum[nt] = bias1[col] + bias2[col];
  }
#pragma unroll
  for (int mt = 0; mt < 4; mt++) {
    const int row = m0 + mb + mt * 16 + quad * 4;
#pragma unroll
    for (int nt = 0; nt < 4; nt++) {
      const int col = n0 + nb + nt * 16 + r16;
      float* Cp = C + (size_t)row * N + col;
#pragma unroll
      for (int reg = 0; reg < 4; reg++)
        Cp[(size_t)reg * N] = acc[mt][nt][reg] + bsum[nt];
    }
  }
}

// ---------------- attention score GEMM, split-bf16 MFMA, fused tanh*ctx ----------
__global__ __launch_bounds__(256, 2) void attn_gemm(
    const float* __restrict__ X, const float* __restrict__ W,
    const float* __restrict__ mlp_b, const float* __restrict__ ctx,
    float* __restrict__ scores, int M, int N, int K)
{
  __shared__ short Xh[128 * LDK], Xl[128 * LDK];
  __shared__ short Wh[128 * LDK], Wl[128 * LDK];
  const int tid = threadIdx.x;
  const int m0 = blockIdx.y * 128, n0 = blockIdx.x * 128;

  const int sr = tid >> 3;
  const int sc = (tid & 7) * 4;
  const float* px[4];
  const float* pw[4];
#pragma unroll
  for (int p = 0; p < 4; p++) {
    px[p] = X + (size_t)(m0 + sr + p * 32) * K;
    pw[p] = W + (size_t)(n0 + sr + p * 32) * K;
  }

  const int lane = tid & 63, w = tid >> 6;
  const int mb = (w & 1) * 64, nb = (w >> 1) * 64;
  const int r16 = lane & 15, quad = lane >> 4;

  f32x4 acc[4][4];
#pragma unroll
  for (int i = 0; i < 4; i++)
#pragma unroll
    for (int j = 0; j < 4; j++) acc[i][j] = (f32x4){0.f, 0.f, 0.f, 0.f};

  for (int k0 = 0; k0 < K; k0 += 32) {
    const int gk = k0 + sc;
#pragma unroll
    for (int p = 0; p < 4; p++) {
      float4 xv = *(const float4*)(px[p] + gk);
      float4 wv = *(const float4*)(pw[p] + gk);
      const int ro = (sr + p * 32) * LDK + sc;
      split_f4(xv, &Xh[ro], &Xl[ro]);
      split_f4(wv, &Wh[ro], &Wl[ro]);
    }
    __syncthreads();

    bf16x8 ah[4], al[4], bh[4], bl[4];
#pragma unroll
    for (int mt = 0; mt < 4; mt++) {
      const int ro = (mb + mt * 16 + r16) * LDK + quad * 8;
      ah[mt] = *(const bf16x8*)&Xh[ro];
      al[mt] = *(const bf16x8*)&Xl[ro];
    }
#pragma unroll
    for (int nt = 0; nt < 4; nt++) {
      const int ro = (nb + nt * 16 + r16) * LDK + quad * 8;
      bh[nt] = *(const bf16x8*)&Wh[ro];
      bl[nt] = *(const bf16x8*)&Wl[ro];
    }
#pragma unroll
    for (int mt = 0; mt < 4; mt++)
#pragma unroll
      for (int nt = 0; nt < 4; nt++) {
        acc[mt][nt] = __builtin_amdgcn_mfma_f32_16x16x32_bf16(ah[mt], bh[nt], acc[mt][nt], 0, 0, 0);
        acc[mt][nt] = __builtin_amdgcn_mfma_f32_16x16x32_bf16(ah[mt], bl[nt], acc[mt][nt], 0, 0, 0);
        acc[mt][nt] = __builtin_amdgcn_mfma_f32_16x16x32_bf16(al[mt], bh[nt], acc[mt][nt], 0, 0, 0);
      }
    __syncthreads();
  }

  float bb4[4], cc4[4];
#pragma unroll
  for (int nt = 0; nt < 4; nt++) {
    const int col = n0 + nb + nt * 16 + r16;
    bb4[nt] = mlp_b[col];
    cc4[nt] = ctx[col];
  }
#pragma unroll
  for (int mt = 0; mt < 4; mt++) {
#pragma unroll
    for (int reg = 0; reg < 4; reg++) {
      float ssum = 0.f;
#pragma unroll
      for (int nt = 0; nt < 4; nt++)
        ssum += tanhfast(acc[mt][nt][reg] + bb4[nt]) * cc4[nt];
      ssum += __shfl_xor(ssum, 1);
      ssum += __shfl_xor(ssum, 2);
      ssum += __shfl_xor(ssum, 4);
      ssum += __shfl_xor(ssum, 8);
      if (r16 == 0)
        atomicAdd(&scores[m0 + mb + mt * 16 + quad * 4 + reg], ssum);
    }
  }
}

// ---------------- LSTM recurrence chunk -- R12: 32 batches/block, 64 blocks ------
// blk = s*8 + d*4 + p: s = hdim slice (s*32..+31), d = dir, p = batch quarter
// (batches p*32..p*32+31 as supergroups u=0,1 of 16). Partners (same d,p) share XCD.
// Per step: MFMA SG0,SG1 ([16x256]@[256x128], all m rows valid) -> barrier ->
// cell updates + ring stores -> x prefetch -> spin-stage SG0,SG1 -> barrier.
__global__ __launch_bounds__(256, 1) void lstm_rec(
    const float* __restrict__ xgF, const float* __restrict__ xgR,
    const float* __restrict__ whF, const float* __restrict__ whR,
    const int* __restrict__ lengths, float* __restrict__ hout,
    float* __restrict__ ring, float* __restrict__ bbuf, float* __restrict__ cbuf,
    int t0)
{
  __shared__ short Ah[2][16 * LDA];   // h(t-1) hi-plane per supergroup
  __shared__ short Al[2][16 * LDA];   // lo-plane
  __shared__ float gbuf[2][16 * 128]; // gate pre-acts: [rb][gate*32 + hl]

  const int tid = threadIdx.x;
  const int blk = blockIdx.x;
  const int s = blk >> 3;
  const int d = (blk >> 2) & 1;
  const int p = blk & 3;
  const int bbase = p * 32;
  const float* __restrict__ xg = d ? xgR : xgF;
  const float* __restrict__ wh = d ? whR : whF;

  const int lane = tid & 63;
  const int w = tid >> 6;              // wave index == gate index
  const int r16 = lane & 15, quad = lane >> 4;

  // staging mapping: thread stages row rb (0..15), dwords kc..kc+15
  const int rb = tid >> 4;
  const int kc = (tid & 15) * 16;
  // cell mapping: thread owns cells (bbase + u*16 + half*8 + q, s*32+hl)
  const int q = tid >> 5;              // 0..7
  const int hl = tid & 31;             // 0..31
  const int hdim = s * 32 + hl;

  // ---- weight fragments (hi/lo bf16), once: 128 VGPR, statically indexed ----
  bf16x8 wbh[2][8], wbl[2][8];
#pragma unroll
  for (int nt = 0; nt < 2; nt++)
#pragma unroll
    for (int kt = 0; kt < 8; kt++) {
      const float* wr = wh + (size_t)(w * 256 + s * 32 + nt * 16 + r16) * 256
                           + kt * 32 + quad * 8;
      float4 v0 = *(const float4*)(wr);
      float4 v1 = *(const float4*)(wr + 4);
      split8(v0, v1, &wbh[nt][kt], &wbl[nt][kt]);
    }

  // ---- initial h(t0-1), c, lengths, x ----
  float cc[2][2];
  int   lbv[2][2];
  float xreg[2][2][4];
#pragma unroll
  for (int u = 0; u < 2; u++)
#pragma unroll
    for (int hf = 0; hf < 2; hf++) {
      const int b = bbase + u * 16 + hf * 8 + q;
      int lb = lengths[b]; if (lb < 1) lb = 1;
      lbv[u][hf] = lb;
      const float* xr = xg + (size_t)b * 1024 + hdim;
      xreg[u][hf][0] = xr[0];   xreg[u][hf][1] = xr[256];
      xreg[u][hf][2] = xr[512]; xreg[u][hf][3] = xr[768];
    }

  if (t0 == 0) {
    int* za = (int*)&Ah[0][0];
    int* zb = (int*)&Al[0][0];
    for (int i = tid; i < (2 * 16 * LDA) / 2; i += 256) { za[i] = 0; zb[i] = 0; }
#pragma unroll
    for (int u = 0; u < 2; u++)
#pragma unroll
      for (int hf = 0; hf < 2; hf++) cc[u][hf] = 0.f;
  } else {
#pragma unroll
    for (int u = 0; u < 2; u++) {
      const float* src = bbuf + ((size_t)d * 128 + bbase + u * 16 + rb) * 256 + kc;
      float4 v0 = *(const float4*)(src);
      float4 v1 = *(const float4*)(src + 4);
      float4 v2 = *(const float4*)(src + 8);
      float4 v3 = *(const float4*)(src + 12);
      bf16x8 hv, lv;
      split8(v0, v1, &hv, &lv);
      *(bf16x8*)&Ah[u][rb * LDA + kc] = hv;
      *(bf16x8*)&Al[u][rb * LDA + kc] = lv;
      split8(v2, v3, &hv, &lv);
      *(bf16x8*)&Ah[u][rb * LDA + kc + 8] = hv;
      *(bf16x8*)&Al[u][rb * LDA + kc + 8] = lv;
#pragma unroll
      for (int hf = 0; hf < 2; hf++)
        cc[u][hf] = cbuf[((size_t)d * 128 + bbase + u * 16 + hf * 8 + q) * 256 + hdim];
    }
  }
  __syncthreads();

  const int tend = t0 + TC;
  for (int t = t0; t < tend; t++) {
    const int slot = t - t0;
    const bool last = (t == tend - 1);

    // ---- MFMA gate matvec per supergroup: 48 MFMAs, 6 independent chains ----
#pragma unroll
    for (int u = 0; u < 2; u++) {
      f32x4 aH0 = {0.f,0.f,0.f,0.f}, aM0 = {0.f,0.f,0.f,0.f}, aL0 = {0.f,0.f,0.f,0.f};
      f32x4 aH1 = {0.f,0.f,0.f,0.f}, aM1 = {0.f,0.f,0.f,0.f}, aL1 = {0.f,0.f,0.f,0.f};
#pragma unroll
      for (int kt = 0; kt < 8; kt++) {
        const int ro = r16 * LDA + kt * 32 + quad * 8;
        bf16x8 ahf = *(const bf16x8*)&Ah[u][ro];
        bf16x8 alf = *(const bf16x8*)&Al[u][ro];
        aH0 = MFMA16(ahf, wbh[0][kt], aH0);
        aM0 = MFMA16(ahf, wbl[0][kt], aM0);
        aL0 = MFMA16(alf, wbh[0][kt], aL0);
        aH1 = MFMA16(ahf, wbh[1][kt], aH1);
        aM1 = MFMA16(ahf, wbl[1][kt], aM1);
        aL1 = MFMA16(alf, wbh[1][kt], aL1);
      }
      // C layout: row m = quad*4+reg (batch 0..15), col n = r16
#pragma unroll
      for (int reg = 0; reg < 4; reg++) {
        gbuf[u][(quad * 4 + reg) * 128 + w * 32 + r16]      = aH0[reg] + aM0[reg] + aL0[reg];
        gbuf[u][(quad * 4 + reg) * 128 + w * 32 + 16 + r16] = aH1[reg] + aM1[reg] + aL1[reg];
      }
    }
    __syncthreads();   // gbuf ready; A reads complete

    // ---- cell updates + ring/hout stores ----
#pragma unroll
    for (int u = 0; u < 2; u++)
#pragma unroll
      for (int hf = 0; hf < 2; hf++) {
        const int rbq = hf * 8 + q;
        const int b = bbase + u * 16 + rbq;
        const float gi = gbuf[u][rbq * 128 +       hl] + xreg[u][hf][0];
        const float gf = gbuf[u][rbq * 128 +  32 + hl] + xreg[u][hf][1];
        const float gg = gbuf[u][rbq * 128 +  64 + hl] + xreg[u][hf][2];
        const float go = gbuf[u][rbq * 128 +  96 + hl] + xreg[u][hf][3];
        const float si = sigf(gi), sf = sigf(gf);
        const float tg = tanhfast(gg), so = sigf(go);
        float c = sf * cc[u][hf] + si * tg;
        cc[u][hf] = c;
        const float h = so * tanhfast(c);
        if (!last) {
          __hip_atomic_store(&ring[(((size_t)slot * 2 + d) * 128 + b) * 256 + hdim], h,
                             __ATOMIC_RELAXED, __HIP_MEMORY_SCOPE_AGENT);
        } else {
          bbuf[((size_t)d * 128 + b) * 256 + hdim] = h;
        }
        const int lb = lbv[u][hf];
        const int tin = d ? ((t < lb) ? (lb - 1 - t) : t) : t;
        hout[((size_t)tin * 128 + b) * 512 + d * 256 + hdim] = h;
      }

    if (!last) {
      // prefetch x(t+1)
#pragma unroll
      for (int u = 0; u < 2; u++)
#pragma unroll
        for (int hf = 0; hf < 2; hf++) {
          const int b = bbase + u * 16 + hf * 8 + q;
          const float* xn = xg + ((size_t)(t + 1 - t0) * 128 + b) * 1024 + hdim;
          xreg[u][hf][0] = xn[0];   xreg[u][hf][1] = xn[256];
          xreg[u][hf][2] = xn[512]; xreg[u][hf][3] = xn[768];
        }

      // spin-stage h(t) for both supergroups: 16 dwords/thread each
#pragma unroll
      for (int u = 0; u < 2; u++) {
        const unsigned* su = (const unsigned*)(ring +
            (((size_t)slot * 2 + d) * 128 + bbase + u * 16 + rb) * 256 + kc);
        unsigned uv[16];
        int it = 0;
        for (;;) {
          bool ok = true;
#pragma unroll
          for (int j = 0; j < 16; j++) {
            uv[j] = __hip_atomic_load(&su[j],
                                      __ATOMIC_RELAXED, __HIP_MEMORY_SCOPE_AGENT);
            ok &= (uv[j] != 0xFFFFFFFFu);
          }
          if (ok || ++it >= 20000) break;
        }
        float4 v0, v1;
        bf16x8 hv, lv;
        v0.x = __uint_as_float(uv[0]);  v0.y = __uint_as_float(uv[1]);
        v0.z = __uint_as_float(uv[2]);  v0.w = __uint_as_float(uv[3]);
        v1.x = __uint_as_float(uv[4]);  v1.y = __uint_as_float(uv[5]);
        v1.z = __uint_as_float(uv[6]);  v1.w = __uint_as_float(uv[7]);
        split8(v0, v1, &hv, &lv);
        *(bf16x8*)&Ah[u][rb * LDA + kc] = hv;
        *(bf16x8*)&Al[u][rb * LDA + kc] = lv;
        v0.x = __uint_as_float(uv[8]);  v0.y = __uint_as_float(uv[9]);
        v0.z = __uint_as_float(uv[10]); v0.w = __uint_as_float(uv[11]);
        v1.x = __uint_as_float(uv[12]); v1.y = __uint_as_float(uv[13]);
        v1.z = __uint_as_float(uv[14]); v1.w = __uint_as_float(uv[15]);
        split8(v0, v1, &hv, &lv);
        *(bf16x8*)&Ah[u][rb * LDA + kc + 8] = hv;
        *(bf16x8*)&Al[u][rb * LDA + kc + 8] = lv;
      }
      __syncthreads();   // A staged for step t+1
    }
  }
#pragma unroll
  for (int u = 0; u < 2; u++)
#pragma unroll
    for (int hf = 0; hf < 2; hf++)
      cbuf[((size_t)d * 128 + bbase + u * 16 + hf * 8 + q) * 256 + hdim] = cc[u][hf];
}

// ---------------- masked softmax over t + weighted sum ----------------
__global__ __launch_bounds__(256) void attn_final(
    const float* __restrict__ h2, const float* __restrict__ scores,
    const int* __restrict__ lengths, float* __restrict__ out)
{
  __shared__ float sl[256];
  __shared__ float red[256];
  const int b = blockIdx.x, tid = threadIdx.x;
  int lb = lengths[b]; if (lb < 1) lb = 1;
  const float sc = scores[(size_t)tid * 128 + b];
  const bool valid = (tid < lb);
  red[tid] = valid ? sc : -1e30f;
  __syncthreads();
  for (int off = 128; off > 0; off >>= 1) {
    if (tid < off) red[tid] = fmaxf(red[tid], red[tid + off]);
    __syncthreads();
  }
  const float mx = red[0];
  __syncthreads();
  const float p = valid ? __expf(sc - mx) : 0.f;
  red[tid] = p;
  __syncthreads();
  for (int off = 128; off > 0; off >>= 1) {
    if (tid < off) red[tid] += red[tid + off];
    __syncthreads();
  }
  const float inv = 1.f / red[0];
  __syncthreads();
  sl[tid] = p * inv;
  __syncthreads();

  float ax = 0.f, ay = 0.f;
  const int dd = tid * 2;
  for (int t = 0; t < 256; t++) {
    const float w = sl[t];
    if (w != 0.f) {
      const float* row = h2 + ((size_t)t * 128 + b) * 512 + dd;
      ax += w * row[0];
      ay += w * row[1];
    }
  }
  float2 r; r.x = ax; r.y = ay;
  *(float2*)(out + (size_t)b * 512 + dd) = r;
}

// ---------------- launch ----------------
extern "C" void kernel_launch(void* const* d_in, const int* in_sizes, int n_in,
                              void* d_out, int out_size, void* d_ws, size_t ws_size,
                              hipStream_t stream) {
  (void)in_sizes; (void)n_in; (void)out_size; (void)ws_size;
  const float* x        = (const float*)d_in[0];
  const int*   lengths  = (const int*)d_in[1];
  const float* w_ih_l0  = (const float*)d_in[2];
  const float* w_hh_l0  = (const float*)d_in[3];
  const float* b_ih_l0  = (const float*)d_in[4];
  const float* b_hh_l0  = (const float*)d_in[5];
  const float* w_ih_l0r = (const float*)d_in[6];
  const float* w_hh_l0r = (const float*)d_in[7];
  const float* b_ih_l0r = (const float*)d_in[8];
  const float* b_hh_l0r = (const float*)d_in[9];
  const float* w_ih_l1  = (const float*)d_in[10];
  const float* w_hh_l1  = (const float*)d_in[11];
  const float* b_ih_l1  = (const float*)d_in[12];
  const float* b_hh_l1  = (const float*)d_in[13];
  const float* w_ih_l1r = (const float*)d_in[14];
  const float* w_hh_l1r = (const float*)d_in[15];
  const float* b_ih_l1r = (const float*)d_in[16];
  const float* b_hh_l1r = (const float*)d_in[17];
  const float* mlp_w    = (const float*)d_in[18];
  const float* mlp_b    = (const float*)d_in[19];
  const float* ctx      = (const float*)d_in[20];
  float* out = (float*)d_out;

  // workspace layout (floats): ~219 MB
  float* ws = (float*)d_ws;
  const size_t XGC    = (size_t)TC * B_ * G4H;        // 8,388,608
  const size_t H_SZ   = (size_t)T_ * B_ * H2;         // 16,777,216
  const size_t RINGSZ = (size_t)TC * 2 * B_ * H_;     // 4,194,304 floats = 16 MB
  float* xgA    = ws;
  float* xgB    = xgA + XGC;
  float* h1     = xgB + XGC;
  float* h2     = h1 + H_SZ;
  float* ring   = h2 + H_SZ;
  float* bbuf   = ring + RINGSZ;                      // 65,536
  float* cbuf   = bbuf + 65536;                       // 65,536
  float* scores = cbuf + 65536;                       // 32,768

  (void)hipMemsetAsync(scores, 0, 32768 * 4, stream);

  dim3 blk(256);
  const dim3 pgrid(G4H / 128, TC, 2);   // (8, 64, 2 directions)

  // layer 0 (K=300), chunked over time
  for (int c = 0; c < T_ / TC; c++) {
    const int t0 = c * TC;
    proj_gemm2<<<pgrid, blk, 0, stream>>>(x, w_ih_l0, w_ih_l0r,
                                          b_ih_l0, b_hh_l0, b_ih_l0r, b_hh_l0r,
                                          xgA, xgB, G4H, D_, lengths, t0);
    (void)hipMemsetAsync(ring, 0xFF, RINGSZ * 4, stream);   // sentinel = 0xFFFFFFFF
    lstm_rec<<<64, blk, 0, stream>>>(xgA, xgB, w_hh_l0, w_hh_l0r, lengths, h1,
                                     ring, bbuf, cbuf, t0);
  }
  // layer 1 (K=512)
  for (int c = 0; c < T_ / TC; c++) {
    const int t0 = c * TC;
    proj_gemm2<<<pgrid, blk, 0, stream>>>(h1, w_ih_l1, w_ih_l1r,
                                          b_ih_l1, b_hh_l1, b_ih_l1r, b_hh_l1r,
                                          xgA, xgB, G4H, H2, lengths, t0);
    (void)hipMemsetAsync(ring, 0xFF, RINGSZ * 4, stream);
    lstm_rec<<<64, blk, 0, stream>>>(xgA, xgB, w_hh_l1, w_hh_l1r, lengths, h2,
                                     ring, bbuf, cbuf, t0);
  }
  // attention (M=32768, N=512, K=512)
  attn_gemm<<<dim3(H2 / 128, (T_ * B_) / 128), blk, 0, stream>>>(h2, mlp_w, mlp_b, ctx, scores, T_ * B_, H2, H2);
  attn_final<<<B_, blk, 0, stream>>>(h2, scores, lengths, out);
}

// Round 4
// 2761.889 us; speedup vs baseline: 1.4894x; 1.4894x over previous
//
#include <hip/hip_runtime.h>

// SentenceEncodingRNN2: 2-layer BiLSTM (T=256,B=128,D=300,H=256) + attention pooling.
// Round 13: cheap exchange. R12 post-mortem: regression (191->411us) was POLL COST,
//   not store->visible latency -- each spin pass issued 32 scattered 4B atomic loads
//   (64 distinct L2 lines per instruction, each line re-touched 16x) ~= 2048 line
//   transactions/pass. Fix, keeping R12's 64-block structure:
//   (a) producers pack h as u32 (hi_bf16<<16 | lo_bf16): half the ring bytes, split
//       done once by producer instead of 8x by consumers;
//   (b) consumers poll with lane-consecutive u64 atomic loads (wave = 512B
//       contiguous, ~128 line transactions/pass, 16x cheaper), unpack via 4 bit-ops
//       straight into Ah/Al (2 lanes/bank LDS writes = free).
//   proj_gemm2 / attn_gemm / attn_final unchanged.

#define T_ 256
#define B_ 128
#define D_ 300
#define H_ 256
#define G4H 1024   // 4*H
#define H2 512     // 2*H
#define TC 64      // time-chunk length
#define LDK 40     // proj/attn LDS k-stride in bf16 (80 B rows)
#define LDA 264    // lstm A-tile LDS k-stride in bf16 (256+8)

typedef __attribute__((ext_vector_type(8))) short bf16x8;
typedef __attribute__((ext_vector_type(4))) short short4v;
typedef __attribute__((ext_vector_type(4))) float f32x4;

#define MFMA16(a, b, c) __builtin_amdgcn_mfma_f32_16x16x32_bf16(a, b, c, 0, 0, 0)

// ---------------- helpers ----------------
__device__ __forceinline__ float sigf(float x) { return 1.f / (1.f + __expf(-x)); }
__device__ __forceinline__ float tanhfast(float x) { return 2.f / (1.f + __expf(-2.f * x)) - 1.f; }

__device__ __forceinline__ short hi_bf16(float x) {
  return (short)(__float_as_uint(x) >> 16);
}
__device__ __forceinline__ short lo_bf16(float x) {
  float lo = x - __uint_as_float(__float_as_uint(x) & 0xFFFF0000u);
  return (short)(__float_as_uint(lo) >> 16);
}

__device__ __forceinline__ void split_f4(const float4 v, short* hp, short* lp) {
  short4v h, l;
  h.x = hi_bf16(v.x); l.x = lo_bf16(v.x);
  h.y = hi_bf16(v.y); l.y = lo_bf16(v.y);
  h.z = hi_bf16(v.z); l.z = lo_bf16(v.z);
  h.w = hi_bf16(v.w); l.w = lo_bf16(v.w);
  *(short4v*)hp = h;
  *(short4v*)lp = l;
}

__device__ __forceinline__ void split8(const float4 v0, const float4 v1,
                                       bf16x8* hp, bf16x8* lp) {
  bf16x8 h, l;
  h[0] = hi_bf16(v0.x); l[0] = lo_bf16(v0.x);
  h[1] = hi_bf16(v0.y); l[1] = lo_bf16(v0.y);
  h[2] = hi_bf16(v0.z); l[2] = lo_bf16(v0.z);
  h[3] = hi_bf16(v0.w); l[3] = lo_bf16(v0.w);
  h[4] = hi_bf16(v1.x); l[4] = lo_bf16(v1.x);
  h[5] = hi_bf16(v1.y); l[5] = lo_bf16(v1.y);
  h[6] = hi_bf16(v1.z); l[6] = lo_bf16(v1.z);
  h[7] = hi_bf16(v1.w); l[7] = lo_bf16(v1.w);
  *hp = h; *lp = l;
}

// ---------------- dual-direction projection GEMM, split-bf16 MFMA ----------------
__global__ __launch_bounds__(256, 2) void proj_gemm2(
    const float* __restrict__ X,
    const float* __restrict__ W0, const float* __restrict__ W1,
    const float* __restrict__ b1f, const float* __restrict__ b2f,
    const float* __restrict__ b1r, const float* __restrict__ b2r,
    float* __restrict__ C0, float* __restrict__ C1,
    int N, int K, const int* __restrict__ lengths, int t0)
{
  __shared__ short Xh[128 * LDK], Xl[128 * LDK];
  __shared__ short Wh[128 * LDK], Wl[128 * LDK];
  const int rev = blockIdx.z;
  const float* __restrict__ W = rev ? W1 : W0;
  const float* __restrict__ bias1 = rev ? b1r : b1f;
  const float* __restrict__ bias2 = rev ? b2r : b2f;
  float* __restrict__ C = rev ? C1 : C0;

  const int tid = threadIdx.x;
  const int m0 = blockIdx.y * 128, n0 = blockIdx.x * 128;
  const int s_step = t0 + blockIdx.y;

  const int sr = tid >> 3;
  const int sc = (tid & 7) * 4;
  const float* px[4];
  const float* pw[4];
#pragma unroll
  for (int p = 0; p < 4; p++) {
    const int r = sr + p * 32;          // r == batch index within tile
    int ss = s_step;
    if (rev) {
      int lb = lengths[r]; if (lb < 1) lb = 1;
      ss = (s_step < lb) ? (lb - 1 - s_step) : s_step;
    }
    px[p] = X + (size_t)(ss * 128 + r) * K;
    pw[p] = W + (size_t)(n0 + r) * K;
  }

  const int lane = tid & 63, w = tid >> 6;
  const int mb = (w & 1) * 64, nb = (w >> 1) * 64;
  const int r16 = lane & 15, quad = lane >> 4;

  f32x4 acc[4][4];
#pragma unroll
  for (int i = 0; i < 4; i++)
#pragma unroll
    for (int j = 0; j < 4; j++) acc[i][j] = (f32x4){0.f, 0.f, 0.f, 0.f};

  for (int k0 = 0; k0 < K; k0 += 32) {
    const int gk = k0 + sc;
    const bool kin = (gk < K);          // K % 4 == 0 -> whole float4 in/out
#pragma unroll
    for (int p = 0; p < 4; p++) {
      float4 xv = {0.f, 0.f, 0.f, 0.f}, wv = {0.f, 0.f, 0.f, 0.f};
      if (kin) { xv = *(const float4*)(px[p] + gk); wv = *(const float4*)(pw[p] + gk); }
      const int ro = (sr + p * 32) * LDK + sc;
      split_f4(xv, &Xh[ro], &Xl[ro]);
      split_f4(wv, &Wh[ro], &Wl[ro]);
    }
    __syncthreads();

    bf16x8 ah[4], al[4], bh[4], bl[4];
#pragma unroll
    for (int mt = 0; mt < 4; mt++) {
      const int ro = (mb + mt * 16 + r16) * LDK + quad * 8;
      ah[mt] = *(const bf16x8*)&Xh[ro];
      al[mt] = *(const bf16x8*)&Xl[ro];
    }
#pragma unroll
    for (int nt = 0; nt < 4; nt++) {
      const int ro = (nb + nt * 16 + r16) * LDK + quad * 8;
      bh[nt] = *(const bf16x8*)&Wh[ro];
      bl[nt] = *(const bf16x8*)&Wl[ro];
    }
#pragma unroll
    for (int mt = 0; mt < 4; mt++)
#pragma unroll
      for (int nt = 0; nt < 4; nt++) {
        acc[mt][nt] = __builtin_amdgcn_mfma_f32_16x16x32_bf16(ah[mt], bh[nt], acc[mt][nt], 0, 0, 0);
        acc[mt][nt] = __builtin_amdgcn_mfma_f32_16x16x32_bf16(ah[mt], bl[nt], acc[mt][nt], 0, 0, 0);
        acc[mt][nt] = __builtin_amdgcn_mfma_f32_16x16x32_bf16(al[mt], bh[nt], acc[mt][nt], 0, 0, 0);
      }
    __syncthreads();
  }

  float bsum[4];
#pragma unroll
  for (int nt = 0; nt < 4; nt++) {
    const int col = n0 + nb + nt * 16 + r16;
    bsum[nt] = bias1[col] + bias2[col];
  }
#pragma unroll
  for (int mt = 0; mt < 4; mt++) {
    const int row = m0 + mb + mt * 16 + quad * 4;
#pragma unroll
    for (int nt = 0; nt < 4; nt++) {
      const int col = n0 + nb + nt * 16 + r16;
      float* Cp = C + (size_t)row * N + col;
#pragma unroll
      for (int reg = 0; reg < 4; reg++)
        Cp[(size_t)reg * N] = acc[mt][nt][reg] + bsum[nt];
    }
  }
}

// ---------------- attention score GEMM, split-bf16 MFMA, fused tanh*ctx ----------
__global__ __launch_bounds__(256, 2) void attn_gemm(
    const float* __restrict__ X, const float* __restrict__ W,
    const float* __restrict__ mlp_b, const float* __restrict__ ctx,
    float* __restrict__ scores, int M, int N, int K)
{
  __shared__ short Xh[128 * LDK], Xl[128 * LDK];
  __shared__ short Wh[128 * LDK], Wl[128 * LDK];
  const int tid = threadIdx.x;
  const int m0 = blockIdx.y * 128, n0 = blockIdx.x * 128;

  const int sr = tid >> 3;
  const int sc = (tid & 7) * 4;
  const float* px[4];
  const float* pw[4];
#pragma unroll
  for (int p = 0; p < 4; p++) {
    px[p] = X + (size_t)(m0 + sr + p * 32) * K;
    pw[p] = W + (size_t)(n0 + sr + p * 32) * K;
  }

  const int lane = tid & 63, w = tid >> 6;
  const int mb = (w & 1) * 64, nb = (w >> 1) * 64;
  const int r16 = lane & 15, quad = lane >> 4;

  f32x4 acc[4][4];
#pragma unroll
  for (int i = 0; i < 4; i++)
#pragma unroll
    for (int j = 0; j < 4; j++) acc[i][j] = (f32x4){0.f, 0.f, 0.f, 0.f};

  for (int k0 = 0; k0 < K; k0 += 32) {
    const int gk = k0 + sc;
#pragma unroll
    for (int p = 0; p < 4; p++) {
      float4 xv = *(const float4*)(px[p] + gk);
      float4 wv = *(const float4*)(pw[p] + gk);
      const int ro = (sr + p * 32) * LDK + sc;
      split_f4(xv, &Xh[ro], &Xl[ro]);
      split_f4(wv, &Wh[ro], &Wl[ro]);
    }
    __syncthreads();

    bf16x8 ah[4], al[4], bh[4], bl[4];
#pragma unroll
    for (int mt = 0; mt < 4; mt++) {
      const int ro = (mb + mt * 16 + r16) * LDK + quad * 8;
      ah[mt] = *(const bf16x8*)&Xh[ro];
      al[mt] = *(const bf16x8*)&Xl[ro];
    }
#pragma unroll
    for (int nt = 0; nt < 4; nt++) {
      const int ro = (nb + nt * 16 + r16) * LDK + quad * 8;
      bh[nt] = *(const bf16x8*)&Wh[ro];
      bl[nt] = *(const bf16x8*)&Wl[ro];
    }
#pragma unroll
    for (int mt = 0; mt < 4; mt++)
#pragma unroll
      for (int nt = 0; nt < 4; nt++) {
        acc[mt][nt] = __builtin_amdgcn_mfma_f32_16x16x32_bf16(ah[mt], bh[nt], acc[mt][nt], 0, 0, 0);
        acc[mt][nt] = __builtin_amdgcn_mfma_f32_16x16x32_bf16(ah[mt], bl[nt], acc[mt][nt], 0, 0, 0);
        acc[mt][nt] = __builtin_amdgcn_mfma_f32_16x16x32_bf16(al[mt], bh[nt], acc[mt][nt], 0, 0, 0);
      }
    __syncthreads();
  }

  float bb4[4], cc4[4];
#pragma unroll
  for (int nt = 0; nt < 4; nt++) {
    const int col = n0 + nb + nt * 16 + r16;
    bb4[nt] = mlp_b[col];
    cc4[nt] = ctx[col];
  }
#pragma unroll
  for (int mt = 0; mt < 4; mt++) {
#pragma unroll
    for (int reg = 0; reg < 4; reg++) {
      float ssum = 0.f;
#pragma unroll
      for (int nt = 0; nt < 4; nt++)
        ssum += tanhfast(acc[mt][nt][reg] + bb4[nt]) * cc4[nt];
      ssum += __shfl_xor(ssum, 1);
      ssum += __shfl_xor(ssum, 2);
      ssum += __shfl_xor(ssum, 4);
      ssum += __shfl_xor(ssum, 8);
      if (r16 == 0)
        atomicAdd(&scores[m0 + mb + mt * 16 + quad * 4 + reg], ssum);
    }
  }
}

// ---------------- LSTM recurrence chunk -- R13: packed u32 exchange --------------
// blk = s*8 + d*4 + p: s = hdim slice (s*32..+31), d = dir, p = batch quarter
// (batches p*32..p*32+31 as supergroups u=0,1 of 16). Partners (same d,p) share XCD.
// Ring entries are u32 (hi_bf16<<16 | lo_bf16); sentinel 0xFFFFFFFF (impossible for
// real h: both halves would be bf16 NaN patterns of bounded values).
// Per step: MFMA SG0,SG1 -> barrier -> cell updates + packed ring stores ->
// x prefetch -> coalesced u64 spin-stage SG0,SG1 -> barrier.
__global__ __launch_bounds__(256, 1) void lstm_rec(
    const float* __restrict__ xgF, const float* __restrict__ xgR,
    const float* __restrict__ whF, const float* __restrict__ whR,
    const int* __restrict__ lengths, float* __restrict__ hout,
    float* __restrict__ ring, float* __restrict__ bbuf, float* __restrict__ cbuf,
    int t0)
{
  __shared__ short Ah[2][16 * LDA];   // h(t-1) hi-plane per supergroup
  __shared__ short Al[2][16 * LDA];   // lo-plane
  __shared__ float gbuf[2][16 * 128]; // gate pre-acts: [rb][gate*32 + hl]

  const int tid = threadIdx.x;
  const int blk = blockIdx.x;
  const int s = blk >> 3;
  const int d = (blk >> 2) & 1;
  const int p = blk & 3;
  const int bbase = p * 32;
  const float* __restrict__ xg = d ? xgR : xgF;
  const float* __restrict__ wh = d ? whR : whF;

  const int lane = tid & 63;
  const int w = tid >> 6;              // wave index == gate index
  const int r16 = lane & 15, quad = lane >> 4;

  // init-staging mapping (bbuf, f32): thread stages row rb, dwords kc..kc+15
  const int rb = tid >> 4;
  const int kc = (tid & 15) * 16;
  // cell mapping: thread owns cells (bbase + u*16 + hf*8 + q, s*32+hl)
  const int q = tid >> 5;              // 0..7
  const int hl = tid & 31;             // 0..31
  const int hdim = s * 32 + hl;

  // ---- weight fragments (hi/lo bf16), once: 128 VGPR, statically indexed ----
  bf16x8 wbh[2][8], wbl[2][8];
#pragma unroll
  for (int nt = 0; nt < 2; nt++)
#pragma unroll
    for (int kt = 0; kt < 8; kt++) {
      const float* wr = wh + (size_t)(w * 256 + s * 32 + nt * 16 + r16) * 256
                           + kt * 32 + quad * 8;
      float4 v0 = *(const float4*)(wr);
      float4 v1 = *(const float4*)(wr + 4);
      split8(v0, v1, &wbh[nt][kt], &wbl[nt][kt]);
    }

  // ---- initial h(t0-1), c, lengths, x ----
  float cc[2][2];
  int   lbv[2][2];
  float xreg[2][2][4];
#pragma unroll
  for (int u = 0; u < 2; u++)
#pragma unroll
    for (int hf = 0; hf < 2; hf++) {
      const int b = bbase + u * 16 + hf * 8 + q;
      int lb = lengths[b]; if (lb < 1) lb = 1;
      lbv[u][hf] = lb;
      const float* xr = xg + (size_t)b * 1024 + hdim;
      xreg[u][hf][0] = xr[0];   xreg[u][hf][1] = xr[256];
      xreg[u][hf][2] = xr[512]; xreg[u][hf][3] = xr[768];
    }

  if (t0 == 0) {
    int* za = (int*)&Ah[0][0];
    int* zb = (int*)&Al[0][0];
    for (int i = tid; i < (2 * 16 * LDA) / 2; i += 256) { za[i] = 0; zb[i] = 0; }
#pragma unroll
    for (int u = 0; u < 2; u++)
#pragma unroll
      for (int hf = 0; hf < 2; hf++) cc[u][hf] = 0.f;
  } else {
#pragma unroll
    for (int u = 0; u < 2; u++) {
      const float* src = bbuf + ((size_t)d * 128 + bbase + u * 16 + rb) * 256 + kc;
      float4 v0 = *(const float4*)(src);
      float4 v1 = *(const float4*)(src + 4);
      float4 v2 = *(const float4*)(src + 8);
      float4 v3 = *(const float4*)(src + 12);
      bf16x8 hv, lv;
      split8(v0, v1, &hv, &lv);
      *(bf16x8*)&Ah[u][rb * LDA + kc] = hv;
      *(bf16x8*)&Al[u][rb * LDA + kc] = lv;
      split8(v2, v3, &hv, &lv);
      *(bf16x8*)&Ah[u][rb * LDA + kc + 8] = hv;
      *(bf16x8*)&Al[u][rb * LDA + kc + 8] = lv;
#pragma unroll
      for (int hf = 0; hf < 2; hf++)
        cc[u][hf] = cbuf[((size_t)d * 128 + bbase + u * 16 + hf * 8 + q) * 256 + hdim];
    }
  }
  __syncthreads();

  const int tend = t0 + TC;
  for (int t = t0; t < tend; t++) {
    const int slot = t - t0;
    const bool last = (t == tend - 1);

    // ---- MFMA gate matvec per supergroup: 48 MFMAs, 6 independent chains ----
#pragma unroll
    for (int u = 0; u < 2; u++) {
      f32x4 aH0 = {0.f,0.f,0.f,0.f}, aM0 = {0.f,0.f,0.f,0.f}, aL0 = {0.f,0.f,0.f,0.f};
      f32x4 aH1 = {0.f,0.f,0.f,0.f}, aM1 = {0.f,0.f,0.f,0.f}, aL1 = {0.f,0.f,0.f,0.f};
#pragma unroll
      for (int kt = 0; kt < 8; kt++) {
        const int ro = r16 * LDA + kt * 32 + quad * 8;
        bf16x8 ahf = *(const bf16x8*)&Ah[u][ro];
        bf16x8 alf = *(const bf16x8*)&Al[u][ro];
        aH0 = MFMA16(ahf, wbh[0][kt], aH0);
        aM0 = MFMA16(ahf, wbl[0][kt], aM0);
        aL0 = MFMA16(alf, wbh[0][kt], aL0);
        aH1 = MFMA16(ahf, wbh[1][kt], aH1);
        aM1 = MFMA16(ahf, wbl[1][kt], aM1);
        aL1 = MFMA16(alf, wbh[1][kt], aL1);
      }
      // C layout: row m = quad*4+reg (batch 0..15), col n = r16
#pragma unroll
      for (int reg = 0; reg < 4; reg++) {
        gbuf[u][(quad * 4 + reg) * 128 + w * 32 + r16]      = aH0[reg] + aM0[reg] + aL0[reg];
        gbuf[u][(quad * 4 + reg) * 128 + w * 32 + 16 + r16] = aH1[reg] + aM1[reg] + aL1[reg];
      }
    }
    __syncthreads();   // gbuf ready; A reads complete

    // ---- cell updates + packed ring stores / hout stores ----
#pragma unroll
    for (int u = 0; u < 2; u++)
#pragma unroll
      for (int hf = 0; hf < 2; hf++) {
        const int rbq = hf * 8 + q;
        const int b = bbase + u * 16 + rbq;
        const float gi = gbuf[u][rbq * 128 +       hl] + xreg[u][hf][0];
        const float gf = gbuf[u][rbq * 128 +  32 + hl] + xreg[u][hf][1];
        const float gg = gbuf[u][rbq * 128 +  64 + hl] + xreg[u][hf][2];
        const float go = gbuf[u][rbq * 128 +  96 + hl] + xreg[u][hf][3];
        const float si = sigf(gi), sf = sigf(gf);
        const float tg = tanhfast(gg), so = sigf(go);
        float c = sf * cc[u][hf] + si * tg;
        cc[u][hf] = c;
        const float h = so * tanhfast(c);
        if (!last) {
          const unsigned uh = (unsigned)(unsigned short)hi_bf16(h);
          const unsigned ul = (unsigned)(unsigned short)lo_bf16(h);
          const unsigned up = (uh << 16) | ul;
          __hip_atomic_store((unsigned*)&ring[(((size_t)slot * 2 + d) * 128 + b) * 256 + hdim],
                             up, __ATOMIC_RELAXED, __HIP_MEMORY_SCOPE_AGENT);
        } else {
          bbuf[((size_t)d * 128 + b) * 256 + hdim] = h;
        }
        const int lb = lbv[u][hf];
        const int tin = d ? ((t < lb) ? (lb - 1 - t) : t) : t;
        hout[((size_t)tin * 128 + b) * 512 + d * 256 + hdim] = h;
      }

    if (!last) {
      // prefetch x(t+1)
#pragma unroll
      for (int u = 0; u < 2; u++)
#pragma unroll
        for (int hf = 0; hf < 2; hf++) {
          const int b = bbase + u * 16 + hf * 8 + q;
          const float* xn = xg + ((size_t)(t + 1 - t0) * 128 + b) * 1024 + hdim;
          xreg[u][hf][0] = xn[0];   xreg[u][hf][1] = xn[256];
          xreg[u][hf][2] = xn[512]; xreg[u][hf][3] = xn[768];
        }

      // coalesced spin-stage: per sg 2048 qwords; thread polls 8 lane-consecutive
      // u64 (wave = 512B contiguous). qidx = j*256+tid -> row = qidx>>7 (128 qw/row),
      // colq = qidx&127 -> cols 2*colq, 2*colq+1.
#pragma unroll
      for (int u = 0; u < 2; u++) {
        const unsigned long long* su = (const unsigned long long*)(ring +
            (((size_t)slot * 2 + d) * 128 + bbase + u * 16) * 256);
        unsigned long long uv[8];
        int it = 0;
        for (;;) {
          bool ok = true;
#pragma unroll
          for (int j = 0; j < 8; j++) {
            uv[j] = __hip_atomic_load(&su[j * 256 + tid],
                                      __ATOMIC_RELAXED, __HIP_MEMORY_SCOPE_AGENT);
            ok &= ((unsigned)uv[j] != 0xFFFFFFFFu) &
                  ((unsigned)(uv[j] >> 32) != 0xFFFFFFFFu);
          }
          if (ok || ++it >= 20000) break;
        }
#pragma unroll
        for (int j = 0; j < 8; j++) {
          const unsigned v0 = (unsigned)uv[j];
          const unsigned v1 = (unsigned)(uv[j] >> 32);
          const unsigned hw = (v1 & 0xFFFF0000u) | (v0 >> 16);
          const unsigned lw = (v1 << 16) | (v0 & 0xFFFFu);
          const int qidx = j * 256 + tid;
          const int row = qidx >> 7;
          const int colq = qidx & 127;
          *(unsigned*)&Ah[u][row * LDA + colq * 2] = hw;
          *(unsigned*)&Al[u][row * LDA + colq * 2] = lw;
        }
      }
      __syncthreads();   // A staged for step t+1
    }
  }
#pragma unroll
  for (int u = 0; u < 2; u++)
#pragma unroll
    for (int hf = 0; hf < 2; hf++)
      cbuf[((size_t)d * 128 + bbase + u * 16 + hf * 8 + q) * 256 + hdim] = cc[u][hf];
}

// ---------------- masked softmax over t + weighted sum ----------------
__global__ __launch_bounds__(256) void attn_final(
    const float* __restrict__ h2, const float* __restrict__ scores,
    const int* __restrict__ lengths, float* __restrict__ out)
{
  __shared__ float sl[256];
  __shared__ float red[256];
  const int b = blockIdx.x, tid = threadIdx.x;
  int lb = lengths[b]; if (lb < 1) lb = 1;
  const float sc = scores[(size_t)tid * 128 + b];
  const bool valid = (tid < lb);
  red[tid] = valid ? sc : -1e30f;
  __syncthreads();
  for (int off = 128; off > 0; off >>= 1) {
    if (tid < off) red[tid] = fmaxf(red[tid], red[tid + off]);
    __syncthreads();
  }
  const float mx = red[0];
  __syncthreads();
  const float p = valid ? __expf(sc - mx) : 0.f;
  red[tid] = p;
  __syncthreads();
  for (int off = 128; off > 0; off >>= 1) {
    if (tid < off) red[tid] += red[tid + off];
    __syncthreads();
  }
  const float inv = 1.f / red[0];
  __syncthreads();
  sl[tid] = p * inv;
  __syncthreads();

  float ax = 0.f, ay = 0.f;
  const int dd = tid * 2;
  for (int t = 0; t < 256; t++) {
    const float w = sl[t];
    if (w != 0.f) {
      const float* row = h2 + ((size_t)t * 128 + b) * 512 + dd;
      ax += w * row[0];
      ay += w * row[1];
    }
  }
  float2 r; r.x = ax; r.y = ay;
  *(float2*)(out + (size_t)b * 512 + dd) = r;
}

// ---------------- launch ----------------
extern "C" void kernel_launch(void* const* d_in, const int* in_sizes, int n_in,
                              void* d_out, int out_size, void* d_ws, size_t ws_size,
                              hipStream_t stream) {
  (void)in_sizes; (void)n_in; (void)out_size; (void)ws_size;
  const float* x        = (const float*)d_in[0];
  const int*   lengths  = (const int*)d_in[1];
  const float* w_ih_l0  = (const float*)d_in[2];
  const float* w_hh_l0  = (const float*)d_in[3];
  const float* b_ih_l0  = (const float*)d_in[4];
  const float* b_hh_l0  = (const float*)d_in[5];
  const float* w_ih_l0r = (const float*)d_in[6];
  const float* w_hh_l0r = (const float*)d_in[7];
  const float* b_ih_l0r = (const float*)d_in[8];
  const float* b_hh_l0r = (const float*)d_in[9];
  const float* w_ih_l1  = (const float*)d_in[10];
  const float* w_hh_l1  = (const float*)d_in[11];
  const float* b_ih_l1  = (const float*)d_in[12];
  const float* b_hh_l1  = (const float*)d_in[13];
  const float* w_ih_l1r = (const float*)d_in[14];
  const float* w_hh_l1r = (const float*)d_in[15];
  const float* b_ih_l1r = (const float*)d_in[16];
  const float* b_hh_l1r = (const float*)d_in[17];
  const float* mlp_w    = (const float*)d_in[18];
  const float* mlp_b    = (const float*)d_in[19];
  const float* ctx      = (const float*)d_in[20];
  float* out = (float*)d_out;

  // workspace layout (floats): ~219 MB
  float* ws = (float*)d_ws;
  const size_t XGC    = (size_t)TC * B_ * G4H;        // 8,388,608
  const size_t H_SZ   = (size_t)T_ * B_ * H2;         // 16,777,216
  const size_t RINGSZ = (size_t)TC * 2 * B_ * H_;     // 4,194,304 floats = 16 MB
  float* xgA    = ws;
  float* xgB    = xgA + XGC;
  float* h1     = xgB + XGC;
  float* h2     = h1 + H_SZ;
  float* ring   = h2 + H_SZ;
  float* bbuf   = ring + RINGSZ;                      // 65,536
  float* cbuf   = bbuf + 65536;                       // 65,536
  float* scores = cbuf + 65536;                       // 32,768

  (void)hipMemsetAsync(scores, 0, 32768 * 4, stream);

  dim3 blk(256);
  const dim3 pgrid(G4H / 128, TC, 2);   // (8, 64, 2 directions)

  // layer 0 (K=300), chunked over time
  for (int c = 0; c < T_ / TC; c++) {
    const int t0 = c * TC;
    proj_gemm2<<<pgrid, blk, 0, stream>>>(x, w_ih_l0, w_ih_l0r,
                                          b_ih_l0, b_hh_l0, b_ih_l0r, b_hh_l0r,
                                          xgA, xgB, G4H, D_, lengths, t0);
    (void)hipMemsetAsync(ring, 0xFF, RINGSZ * 4, stream);   // sentinel = 0xFFFFFFFF
    lstm_rec<<<64, blk, 0, stream>>>(xgA, xgB, w_hh_l0, w_hh_l0r, lengths, h1,
                                     ring, bbuf, cbuf, t0);
  }
  // layer 1 (K=512)
  for (int c = 0; c < T_ / TC; c++) {
    const int t0 = c * TC;
    proj_gemm2<<<pgrid, blk, 0, stream>>>(h1, w_ih_l1, w_ih_l1r,
                                          b_ih_l1, b_hh_l1, b_ih_l1r, b_hh_l1r,
                                          xgA, xgB, G4H, H2, lengths, t0);
    (void)hipMemsetAsync(ring, 0xFF, RINGSZ * 4, stream);
    lstm_rec<<<64, blk, 0, stream>>>(xgA, xgB, w_hh_l1, w_hh_l1r, lengths, h2,
                                     ring, bbuf, cbuf, t0);
  }
  // attention (M=32768, N=512, K=512)
  attn_gemm<<<dim3(H2 / 128, (T_ * B_) / 128), blk, 0, stream>>>(h2, mlp_w, mlp_b, ctx, scores, T_ * B_, H2, H2);
  attn_final<<<B_, blk, 0, stream>>>(h2, scores, lengths, out);
}